// Round 7
// baseline (395.805 us; speedup 1.0000x reference)
//
#include <hip/hip_runtime.h>
#include <hip/hip_bf16.h>

typedef unsigned int uint;
typedef unsigned short ushort;

constexpr int Bn = 256, Sn = 512, Vn = 32000, Dn = 100, Hn = 75, Ln = 128;
constexpr int EW = 80;    // embW row stride (floats), cols 75..79 zero
constexpr int KP = 96;    // h_all row stride (f16) = MFMA K-pad (3 x 32)
constexpr int W2S = 80;   // w2p row stride (f16)

// workspace layout (float units)
constexpr size_t OFF_EMBW = 0;                          // 32000*80   = 2,560,000 f
constexpr size_t OFF_HALL = OFF_EMBW + (size_t)Vn*EW;   // 131072*96 f16 = 6,291,456 f
constexpr size_t OFF_W2P  = OFF_HALL + (size_t)Bn*Sn*KP/2; // 80*80 f16 = 3200 f
constexpr size_t OFF_WOH  = OFF_W2P + 3200;             // 80*96 f16  = 3840 f
constexpr size_t OFF_WFH  = OFF_WOH + 3840;             // 128*96 f16 = 6144 f

typedef __attribute__((ext_vector_type(2))) _Float16 half2_t;
typedef __attribute__((ext_vector_type(8))) _Float16 half8;
typedef __attribute__((ext_vector_type(4))) float floatx4;

__device__ __forceinline__ ushort f2h(float f){
    union { _Float16 h; ushort u; } v; v.h = (_Float16)f; return v.u;
}
__device__ __forceinline__ half8 as_h8(uint4 u){
    union { uint4 u; half8 h; } v; v.u = u; return v.h;
}
__device__ __forceinline__ float sigmoidf(float z){
    return __builtin_amdgcn_rcpf(1.f + __expf(-z));
}

// ---------------------------------------------------------------------------
// Prep: W2 -> [80][80] f16 (pad 0), Wo -> [80][96] f16, Wfc -> [128][96] f16,
// zero h_all pad cols 80..95 (so k_out never reads garbage).
// ---------------------------------------------------------------------------
__global__ __launch_bounds__(256) void k_wprep(
    const float* __restrict__ W2, const float* __restrict__ Wo,
    const float* __restrict__ Wfc, ushort* __restrict__ w2p,
    ushort* __restrict__ woh, ushort* __restrict__ wfh, ushort* __restrict__ h_all)
{
    const int tid = blockIdx.x*256 + threadIdx.x;
    const int stride = gridDim.x*256;
    for (int i = tid; i < 80*W2S; i += stride){
        int r = i / W2S, k = i % W2S;
        w2p[i] = (r < Hn && k < Hn) ? f2h(W2[r*Hn + k]) : (ushort)0;
    }
    for (int i = tid; i < 80*KP; i += stride){
        int r = i / KP, k = i % KP;
        woh[i] = (r < Hn && k < Hn) ? f2h(Wo[r*Hn + k]) : (ushort)0;
    }
    for (int i = tid; i < Ln*KP; i += stride){
        int l = i / KP, k = i % KP;
        wfh[i] = (k < Hn) ? f2h(Wfc[l*Hn + k]) : (ushort)0;
    }
    // h_all[row][80..95] = 0  (8 uints per row)
    uint* hu = (uint*)h_all;
    for (int i = tid; i < Bn*Sn*8; i += stride){
        int row = i >> 3, c = i & 7;
        hu[(size_t)row*48 + 40 + c] = 0u;
    }
}

// ---------------------------------------------------------------------------
// embW[v][j] = sum_d emb[v][d]*W1[j][d] + b1[j] + b2[j], stride EW=80.
// r7: 4 waves/block; wave w owns col-group j0=19w (j stays WAVE-UNIFORM ->
// W1 row reads remain s_loads). 19 cols/wave instead of 75 -> ~4x less
// latency-serial work per wave. Grid 500 x 256 threads.
// ---------------------------------------------------------------------------
__global__ __attribute__((amdgpu_flat_work_group_size(256,256)))
__attribute__((amdgpu_waves_per_eu(1,1)))
void k_embproj(
    const float* __restrict__ emb, const float* __restrict__ W1,
    const float* __restrict__ b1, const float* __restrict__ b2,
    float* __restrict__ embW)
{
    const int lane = threadIdx.x & 63;
    const int w    = threadIdx.x >> 6;           // col-group 0..3
    const int v = blockIdx.x*64 + lane;
    const float4* ev = (const float4*)(emb + (size_t)v*Dn);
    float e[Dn];
    #pragma unroll
    for (int q = 0; q < Dn/4; ++q){
        float4 x = ev[q];
        e[4*q] = x.x; e[4*q+1] = x.y; e[4*q+2] = x.z; e[4*q+3] = x.w;
    }
    __shared__ float s_out[64*EW];
    const int j0 = w*19;
    const int jend = (w == 3) ? 18 : 19;         // w=3 covers 57..74
    #pragma unroll 2
    for (int jj = 0; jj < jend; ++jj){
        int j = j0 + jj;
        float a0 = b1[j] + b2[j], a1 = 0.f, a2 = 0.f, a3 = 0.f;
        const float* wp = W1 + j*Dn;             // wave-uniform -> s_loads
        #pragma unroll
        for (int d = 0; d < Dn; d += 4){
            a0 += wp[d]*e[d];     a1 += wp[d+1]*e[d+1];
            a2 += wp[d+2]*e[d+2]; a3 += wp[d+3]*e[d+3];
        }
        s_out[lane*EW + j] = (a0+a1) + (a2+a3);
    }
    if (w == 3){
        #pragma unroll
        for (int j = Hn; j < EW; ++j) s_out[lane*EW + j] = 0.f;
    }
    __syncthreads();
    float* dst = embW + (size_t)blockIdx.x*64*EW;
    for (int i = threadIdx.x; i < 64*EW; i += 256) dst[i] = s_out[i];
}

// ---------------------------------------------------------------------------
// Sequential scan: ONE WAVE per batch row. r6 = 164us (770cy/step; busy
// counters ~110cy -> ~660cy latency wait). r7 compresses the chain around
// the single unavoidable cross-lane LDS hop:
//  (1) K-SPLIT: 15 INDEPENDENT MFMAs acc[t][ks] (no C-chaining); partial
//      sums combined by 2 VALU adds -> removes 2 MFMA dep links.
//  (2) xp folded into MFMA C-operand (C = broadcast4 x[16t+m]) -> no add.
//  (3) D-layout trick: lane L holds y[16t+m] for t=0..4 -> sigmoid all 5
//      in parallel, f2h+DPP-pack 5 pairs, combine via v_permlane32_swap
//      (VALU): S={q0.lo|q1.lo}, T={q2.lo|q3.lo}, U={q4.lo|0}. A-frags =
//      12 bpermutes from S/T/U with 4 SHARED loop-invariant addresses
//      va_j = 4*((L&32)+((L&16)>>1)+2j)  [g=0:q.lo[2j], g=1:q.lo[8+2j],
//      g=2:q.hi[2j], g=3:q.hi[8+2j] = h[8g+2j] pairs per K-slice].
//      Store-select = 3 cheap 16-bit cndmasks, off critical path.
// xp staging (r6-proven): 64-step LDS double buffer via global_load_lds,
// one vmcnt drain per chunk; in-loop xp = affine ds_read, 2-deep prefetch.
// ---------------------------------------------------------------------------
__global__ __attribute__((amdgpu_flat_work_group_size(64,64)))
__attribute__((amdgpu_waves_per_eu(1,1)))
void k_rnn(
    const int* __restrict__ X, const float* __restrict__ embW,
    const ushort* __restrict__ w2p, ushort* __restrict__ h_all)
{
    const int b = blockIdx.x;
    const int L = threadIdx.x;
    const int m = L & 15;
    const int g = L >> 4;
    __shared__ int sX[Sn];                         // 2 KB
    __shared__ __align__(16) float xpb[2][64*80];  // 40 KB xp double buffer

    for (int i = L; i < Sn; i += 64) sX[i] = X[b*Sn + i];

    // B-fragments: lane holds W2[n=16t+m][k0..k0+7], k0 = ks*32+g*8.
    half8 bfr[5][3];
    #pragma unroll
    for (int t = 0; t < 5; ++t){
        #pragma unroll
        for (int ks = 0; ks < 3; ++ks){
            int k0 = ks*32 + g*8;
            half8 bv = {};
            if (k0 < 80) bv = *(const half8*)(w2p + (size_t)(16*t + m)*W2S + k0);
            bfr[t][ks] = bv;                     // k0>=80: A is zero there anyway
        }
    }
    __syncthreads();

    // stage chunk c (64 steps x 320B) into xpb[c&1] via global_load_lds.
    auto stage = [&](int c){
        float* buf = xpb[c & 1];
        const int base = c*64;
        #pragma unroll
        for (int k = 0; k < 20; ++k){
            int idx = k*64 + L;
            int cs  = idx / 20;
            int off = idx - cs*20;
            int tok = sX[base + cs];
            const float* src = embW + (size_t)tok*EW + off*4;
            __builtin_amdgcn_global_load_lds(
                (const __attribute__((address_space(1))) uint*)src,
                (__attribute__((address_space(3))) uint*)(buf + k*256),
                16, 0, 0);
        }
    };

    // shared bpermute byte-addresses (loop-invariant), j = pair index 0..3
    const int vbase = (L & 32) + ((L & 16) >> 1);
    const int va0 = 4*(vbase + 0), va1 = 4*(vbase + 2),
              va2 = 4*(vbase + 4), va3 = 4*(vbase + 6);

    ushort* hout = h_all + (size_t)b*Sn*KP;
    uint4 A0 = {}, A1 = {}, A2 = {};             // h_{-1} = 0

    stage(0);
    for (int c = 0; c < 8; ++c){
        __syncthreads();                 // chunk c landed (vmcnt drain, 1/64 steps)
        if (c < 7) stage(c + 1);         // async stage into the other buffer
        const float* xp = xpb[c & 1];
        // xp prefetch (2 deep): 5 values/lane, idx 16t+m
        float xc0 = xp[m], xc1 = xp[16+m], xc2 = xp[32+m], xc3 = xp[48+m], xc4 = xp[64+m];
        float xn0 = xp[80+m], xn1 = xp[96+m], xn2 = xp[112+m], xn3 = xp[128+m], xn4 = xp[144+m];
        for (int t = 0; t < 64; ++t){
            int pf = (t + 2 < 64) ? t + 2 : 63;  // clamped slots never consumed
            const float* xpf = xp + pf*80;
            float xf0 = xpf[m],    xf1 = xpf[16+m], xf2 = xpf[32+m],
                  xf3 = xpf[48+m], xf4 = xpf[64+m];

            half8 af0 = as_h8(A0), af1 = as_h8(A1), af2 = as_h8(A2);

            // 15 INDEPENDENT MFMAs; ks=0 carries the xp C-init
            floatx4 ci0 = {xc0,xc0,xc0,xc0}, ci1 = {xc1,xc1,xc1,xc1},
                    ci2 = {xc2,xc2,xc2,xc2}, ci3 = {xc3,xc3,xc3,xc3},
                    ci4 = {xc4,xc4,xc4,xc4};
            const floatx4 z4 = {};
            floatx4 p00 = __builtin_amdgcn_mfma_f32_16x16x32_f16(af0, bfr[0][0], ci0, 0,0,0);
            floatx4 p10 = __builtin_amdgcn_mfma_f32_16x16x32_f16(af0, bfr[1][0], ci1, 0,0,0);
            floatx4 p20 = __builtin_amdgcn_mfma_f32_16x16x32_f16(af0, bfr[2][0], ci2, 0,0,0);
            floatx4 p30 = __builtin_amdgcn_mfma_f32_16x16x32_f16(af0, bfr[3][0], ci3, 0,0,0);
            floatx4 p40 = __builtin_amdgcn_mfma_f32_16x16x32_f16(af0, bfr[4][0], ci4, 0,0,0);
            floatx4 p01 = __builtin_amdgcn_mfma_f32_16x16x32_f16(af1, bfr[0][1], z4, 0,0,0);
            floatx4 p11 = __builtin_amdgcn_mfma_f32_16x16x32_f16(af1, bfr[1][1], z4, 0,0,0);
            floatx4 p21 = __builtin_amdgcn_mfma_f32_16x16x32_f16(af1, bfr[2][1], z4, 0,0,0);
            floatx4 p31 = __builtin_amdgcn_mfma_f32_16x16x32_f16(af1, bfr[3][1], z4, 0,0,0);
            floatx4 p41 = __builtin_amdgcn_mfma_f32_16x16x32_f16(af1, bfr[4][1], z4, 0,0,0);
            floatx4 p02 = __builtin_amdgcn_mfma_f32_16x16x32_f16(af2, bfr[0][2], z4, 0,0,0);
            floatx4 p12 = __builtin_amdgcn_mfma_f32_16x16x32_f16(af2, bfr[1][2], z4, 0,0,0);
            floatx4 p22 = __builtin_amdgcn_mfma_f32_16x16x32_f16(af2, bfr[2][2], z4, 0,0,0);
            floatx4 p32 = __builtin_amdgcn_mfma_f32_16x16x32_f16(af2, bfr[3][2], z4, 0,0,0);
            floatx4 p42 = __builtin_amdgcn_mfma_f32_16x16x32_f16(af2, bfr[4][2], z4, 0,0,0);

            // y[16t+m] = sum of K-partials (reg 0 = row 4g, rows identical)
            float h0 = sigmoidf((p00[0] + p01[0]) + p02[0]);
            float h1 = sigmoidf((p10[0] + p11[0]) + p12[0]);
            float h2 = sigmoidf((p20[0] + p21[0]) + p22[0]);
            float h3 = sigmoidf((p30[0] + p31[0]) + p32[0]);
            float h4 = sigmoidf((p40[0] + p41[0]) + p42[0]);
            if (m >= 11) h4 = 0.f;               // h[75..79] pad -> 0

            ushort u0 = f2h(h0), u1 = f2h(h1), u2 = f2h(h2),
                   u3 = f2h(h3), u4 = f2h(h4);

            // store h[L] (= t=g slot) and h[64+m] (lanes L<16)
            ushort us = (L < 32) ? ((L < 16) ? u0 : u1)
                                 : ((L < 48) ? u2 : u3);
            int s = c*64 + t;
            hout[(size_t)s*KP + L] = us;
            if (L < 16) hout[(size_t)s*KP + 64 + L] = u4;

            // pack adjacent lanes' f16 pairs (valid on even lanes)
            uint pq0, pq1, pq2, pq3, pq4;
            {
                uint w0=u0, w1=u1, w2=u2, w3=u3, w4=u4;
                uint r0 = (uint)__builtin_amdgcn_update_dpp(0, (int)w0, 0xB1, 0xF, 0xF, true);
                uint r1 = (uint)__builtin_amdgcn_update_dpp(0, (int)w1, 0xB1, 0xF, 0xF, true);
                uint r2 = (uint)__builtin_amdgcn_update_dpp(0, (int)w2, 0xB1, 0xF, 0xF, true);
                uint r3 = (uint)__builtin_amdgcn_update_dpp(0, (int)w3, 0xB1, 0xF, 0xF, true);
                uint r4 = (uint)__builtin_amdgcn_update_dpp(0, (int)w4, 0xB1, 0xF, 0xF, true);
                pq0 = w0 | (r0 << 16); pq1 = w1 | (r1 << 16);
                pq2 = w2 | (r2 << 16); pq3 = w3 | (r3 << 16);
                pq4 = w4 | (r4 << 16);
            }
            // combine: S={q0.lo|q1.lo}, T={q2.lo|q3.lo}, U={q4.lo|0} (VALU swap)
            uint S = pq0, Sb = pq1, T = pq2, Tb = pq3, U = pq4, Ub = 0u;
            asm volatile("s_nop 1\n\t"
                         "v_permlane32_swap_b32 %0, %1\n\t"
                         "v_permlane32_swap_b32 %2, %3\n\t"
                         "v_permlane32_swap_b32 %4, %5"
                         : "+v"(S), "+v"(Sb), "+v"(T), "+v"(Tb), "+v"(U), "+v"(Ub));

            // rebuild A-frags: 12 bpermutes, shared addresses
            A0.x = (uint)__builtin_amdgcn_ds_bpermute(va0, (int)S);
            A0.y = (uint)__builtin_amdgcn_ds_bpermute(va1, (int)S);
            A0.z = (uint)__builtin_amdgcn_ds_bpermute(va2, (int)S);
            A0.w = (uint)__builtin_amdgcn_ds_bpermute(va3, (int)S);
            A1.x = (uint)__builtin_amdgcn_ds_bpermute(va0, (int)T);
            A1.y = (uint)__builtin_amdgcn_ds_bpermute(va1, (int)T);
            A1.z = (uint)__builtin_amdgcn_ds_bpermute(va2, (int)T);
            A1.w = (uint)__builtin_amdgcn_ds_bpermute(va3, (int)T);
            A2.x = (uint)__builtin_amdgcn_ds_bpermute(va0, (int)U);
            A2.y = (uint)__builtin_amdgcn_ds_bpermute(va1, (int)U);
            A2.z = (uint)__builtin_amdgcn_ds_bpermute(va2, (int)U);
            A2.w = (uint)__builtin_amdgcn_ds_bpermute(va3, (int)U);

            xc0=xn0; xc1=xn1; xc2=xn2; xc3=xn3; xc4=xn4;
            xn0=xf0; xn1=xf1; xn2=xf2; xn3=xf3; xn4=xf4;
        }
    }
}

// ---------------------------------------------------------------------------
// Epilogue GEMM via MFMA 16x16x32 f16. Per block: 4 waves x 16 rows.
// Phase1: Z = H(16x96)@Wo^T + bo -> sigmoid -> O f16 in LDS (stride 104);
// Phase2: OUT = O@Wfc^T + bfc.
// C/D frag: col=lane&15, row=(lane>>4)*4+reg (m89-verified, dtype-indep).
// ---------------------------------------------------------------------------
__global__ __launch_bounds__(256) void k_out(
    const ushort* __restrict__ h_all, const ushort* __restrict__ woh,
    const ushort* __restrict__ wfh, const float* __restrict__ bo,
    const float* __restrict__ bfc, float* __restrict__ out)
{
    const int lane = threadIdx.x & 63;
    const int w    = threadIdx.x >> 6;
    const size_t r0 = (size_t)blockIdx.x*64 + w*16;
    const int m = lane & 15;
    const int g = lane >> 4;
    __shared__ __align__(16) ushort o_lds[4][16*104];
    ushort* ot = o_lds[w];
    // zero O pad cols 80..95 (read by k-step 2); wave-local, no barrier needed
    for (int i = lane; i < 128; i += 64){
        int row = i >> 3, cw = i & 7;
        *(uint*)&ot[row*104 + 80 + cw*2] = 0u;
    }
    // ---- Phase 1: Z = H @ Wo^T ----
    floatx4 acc1[5] = {};
    const ushort* hbase = h_all + r0*KP;
    #pragma unroll
    for (int ks = 0; ks < 3; ++ks){
        half8 a = *(const half8*)(hbase + (size_t)m*KP + ks*32 + g*8);
        #pragma unroll
        for (int t = 0; t < 5; ++t){
            half8 bt = *(const half8*)(woh + (16*t + m)*KP + ks*32 + g*8);
            acc1[t] = __builtin_amdgcn_mfma_f32_16x16x32_f16(a, bt, acc1[t], 0, 0, 0);
        }
    }
    // ---- bo + sigmoid -> O (f16, C layout) ----
    #pragma unroll
    for (int t = 0; t < 5; ++t){
        int n = 16*t + m;
        float bias = (n < Hn) ? bo[n] : 0.f;
        #pragma unroll
        for (int r = 0; r < 4; ++r){
            int row = g*4 + r;
            float o = 1.f/(1.f + __expf(-(acc1[t][r] + bias)));
            if (n >= Hn) o = 0.f;              // pad rows -> z=0 -> 0.5; kill
            ot[row*104 + n] = f2h(o);
        }
    }
    // wave-local LDS RAW: in-order DS pipe within a wave; no barrier
    // ---- Phase 2: OUT = O @ Wfc^T ----
    floatx4 acc2[8] = {};
    #pragma unroll
    for (int ks = 0; ks < 3; ++ks){
        half8 a = *(const half8*)(ot + m*104 + ks*32 + g*8);
        #pragma unroll
        for (int t = 0; t < 8; ++t){
            half8 bt = *(const half8*)(wfh + (16*t + m)*KP + ks*32 + g*8);
            acc2[t] = __builtin_amdgcn_mfma_f32_16x16x32_f16(a, bt, acc2[t], 0, 0, 0);
        }
    }
    // ---- bfc + store ----
    float* orow = out + r0*Ln;
    #pragma unroll
    for (int t = 0; t < 8; ++t){
        float bias = bfc[16*t + m];
        #pragma unroll
        for (int r = 0; r < 4; ++r){
            int row = g*4 + r;
            orow[(size_t)row*Ln + 16*t + m] = acc2[t][r] + bias;
        }
    }
}

extern "C" void kernel_launch(void* const* d_in, const int* in_sizes, int n_in,
                              void* d_out, int out_size, void* d_ws, size_t ws_size,
                              hipStream_t stream)
{
    const int*   X   = (const int*)d_in[0];
    const float* emb = (const float*)d_in[1];
    const float* W1  = (const float*)d_in[2];
    const float* b1  = (const float*)d_in[3];
    const float* W2  = (const float*)d_in[4];
    const float* b2  = (const float*)d_in[5];
    const float* Wo  = (const float*)d_in[6];
    const float* bo  = (const float*)d_in[7];
    const float* Wfc = (const float*)d_in[8];
    const float* bfc = (const float*)d_in[9];
    float* out = (float*)d_out;
    float* ws  = (float*)d_ws;

    float*  embW = ws + OFF_EMBW;
    ushort* hall = (ushort*)(ws + OFF_HALL);
    ushort* w2p  = (ushort*)(ws + OFF_W2P);
    ushort* woh  = (ushort*)(ws + OFF_WOH);
    ushort* wfh  = (ushort*)(ws + OFF_WFH);

    k_wprep<<<dim3(512), dim3(256), 0, stream>>>(W2, Wo, Wfc, w2p, woh, wfh, hall);
    k_embproj<<<dim3(Vn/64), dim3(256), 0, stream>>>(emb, W1, b1, b2, embW);
    k_rnn<<<dim3(Bn), dim3(64), 0, stream>>>(X, embW, w2p, hall);
    k_out<<<dim3((Bn*Sn)/64), dim3(256), 0, stream>>>(hall, woh, wfh, bo, bfc, out);
}

// Round 9
// 341.727 us; speedup vs baseline: 1.1583x; 1.1583x over previous
//
#include <hip/hip_runtime.h>
#include <hip/hip_bf16.h>

typedef unsigned int uint;
typedef unsigned short ushort;

constexpr int Bn = 256, Sn = 512, Vn = 32000, Dn = 100, Hn = 75, Ln = 128;
constexpr int EW = 80;    // embW row stride (floats), cols 75..79 zero
constexpr int KP = 96;    // h_all row stride (f16) = MFMA K-pad (3 x 32)
constexpr int W2S = 80;   // w2p row stride (f16)
constexpr float LOG2E = 1.44269504088896f;

// workspace layout (float units)
constexpr size_t OFF_EMBW = 0;                          // 32000*80   = 2,560,000 f
constexpr size_t OFF_HALL = OFF_EMBW + (size_t)Vn*EW;   // 131072*96 f16 = 6,291,456 f
constexpr size_t OFF_W2P  = OFF_HALL + (size_t)Bn*Sn*KP/2; // 80*80 f16 = 3200 f
constexpr size_t OFF_WOH  = OFF_W2P + 3200;             // 80*96 f16  = 3840 f
constexpr size_t OFF_WFH  = OFF_WOH + 3840;             // 128*96 f16 = 6144 f

typedef __attribute__((ext_vector_type(2))) _Float16 half2_t;
typedef __attribute__((ext_vector_type(8))) _Float16 half8;
typedef __attribute__((ext_vector_type(4))) float floatx4;

__device__ __forceinline__ ushort f2h(float f){
    union { _Float16 h; ushort u; } v; v.h = (_Float16)f; return v.u;
}
__device__ __forceinline__ half8 as_h8(uint4 u){
    union { uint4 u; half8 h; } v; v.u = u; return v.h;
}
// z is PRE-SCALED by log2e (weights/xp scaled at prep): sigmoid = rcp(1+2^-z)
__device__ __forceinline__ float sigmoid2f(float z){
    return __builtin_amdgcn_rcpf(1.f + exp2f(-z));
}

// ---------------------------------------------------------------------------
// Prep: W2 -> [80][80] f16 * log2e (exp2-domain recurrence), Wo -> [80][96],
// Wfc -> [128][96] f16; zero h_all pad cols 80..95.
// ---------------------------------------------------------------------------
__global__ __launch_bounds__(256) void k_wprep(
    const float* __restrict__ W2, const float* __restrict__ Wo,
    const float* __restrict__ Wfc, ushort* __restrict__ w2p,
    ushort* __restrict__ woh, ushort* __restrict__ wfh, ushort* __restrict__ h_all)
{
    const int tid = blockIdx.x*256 + threadIdx.x;
    const int stride = gridDim.x*256;
    for (int i = tid; i < 80*W2S; i += stride){
        int r = i / W2S, k = i % W2S;
        w2p[i] = (r < Hn && k < Hn) ? f2h(W2[r*Hn + k] * LOG2E) : (ushort)0;
    }
    for (int i = tid; i < 80*KP; i += stride){
        int r = i / KP, k = i % KP;
        woh[i] = (r < Hn && k < Hn) ? f2h(Wo[r*Hn + k]) : (ushort)0;
    }
    for (int i = tid; i < Ln*KP; i += stride){
        int l = i / KP, k = i % KP;
        wfh[i] = (k < Hn) ? f2h(Wfc[l*Hn + k]) : (ushort)0;
    }
    // h_all[row][80..95] = 0  (8 uints per row)
    uint* hu = (uint*)h_all;
    for (int i = tid; i < Bn*Sn*8; i += stride){
        int row = i >> 3, c = i & 7;
        hu[(size_t)row*48 + 40 + c] = 0u;
    }
}

// ---------------------------------------------------------------------------
// embW[v][j] = (sum_d emb[v][d]*W1[j][d] + b1[j] + b2[j]) * log2e, stride 80.
// r7-proven: 4 waves/block, wave w owns col-group (j wave-uniform -> s_loads).
// ---------------------------------------------------------------------------
__global__ __attribute__((amdgpu_flat_work_group_size(256,256)))
__attribute__((amdgpu_waves_per_eu(1,1)))
void k_embproj(
    const float* __restrict__ emb, const float* __restrict__ W1,
    const float* __restrict__ b1, const float* __restrict__ b2,
    float* __restrict__ embW)
{
    const int lane = threadIdx.x & 63;
    const int w    = threadIdx.x >> 6;           // col-group 0..3
    const int v = blockIdx.x*64 + lane;
    const float4* ev = (const float4*)(emb + (size_t)v*Dn);
    float e[Dn];
    #pragma unroll
    for (int q = 0; q < Dn/4; ++q){
        float4 x = ev[q];
        e[4*q] = x.x; e[4*q+1] = x.y; e[4*q+2] = x.z; e[4*q+3] = x.w;
    }
    __shared__ float s_out[64*EW];
    const int j0 = w*19;
    const int jend = (w == 3) ? 18 : 19;         // w=3 covers 57..74
    #pragma unroll 2
    for (int jj = 0; jj < jend; ++jj){
        int j = j0 + jj;
        float a0 = b1[j] + b2[j], a1 = 0.f, a2 = 0.f, a3 = 0.f;
        const float* wp = W1 + j*Dn;             // wave-uniform -> s_loads
        #pragma unroll
        for (int d = 0; d < Dn; d += 4){
            a0 += wp[d]*e[d];     a1 += wp[d+1]*e[d+1];
            a2 += wp[d+2]*e[d+2]; a3 += wp[d+3]*e[d+3];
        }
        s_out[lane*EW + j] = ((a0+a1) + (a2+a3)) * LOG2E;
    }
    if (w == 3){
        #pragma unroll
        for (int j = Hn; j < EW; ++j) s_out[lane*EW + j] = 0.f;
    }
    __syncthreads();
    float* dst = embW + (size_t)blockIdx.x*64*EW;
    for (int i = threadIdx.x; i < 64*EW; i += 256) dst[i] = s_out[i];
}

// ---------------------------------------------------------------------------
// Sequential scan: ONE WAVE per batch row. r6 structure (best, 164us) with
// surgical chain trims only (r7 post-mortem: VALU clusters on the chain cost
// more than MFMA dep-links save; this round adds NO VALU clusters):
//  (1) 2+1 MFMA split: ks0->ks1 chained, ks2 independent; +2 adds on chain,
//      -1 MFMA dep level.
//  (2) exp2-domain: W2/embW pre-scaled by log2e -> sigmoid = rcp(1+2^-z),
//      no in-loop mul by log2e.
//  (3) source-order overlap: A0/A1 bpermutes (q1) issued BEFORE h2/q2/A2,
//      hiding h2's VALU under the first 8 bpermutes' LDS-pipe latency.
// xp staging (r6-proven): 64-step LDS double buffer via global_load_lds,
// one vmcnt drain per chunk; in-loop xp = affine ds_read, 2-deep prefetch.
// ---------------------------------------------------------------------------
__global__ __attribute__((amdgpu_flat_work_group_size(64,64)))
__attribute__((amdgpu_waves_per_eu(1,1)))
void k_rnn(
    const int* __restrict__ X, const float* __restrict__ embW,
    const ushort* __restrict__ w2p, ushort* __restrict__ h_all)
{
    const int b = blockIdx.x;
    const int L = threadIdx.x;
    const int m = L & 15;
    const int g = L >> 4;
    __shared__ int sX[Sn];                         // 2 KB
    __shared__ __align__(16) float xpb[2][64*80];  // 40 KB xp double buffer

    for (int i = L; i < Sn; i += 64) sX[i] = X[b*Sn + i];

    // B-fragments: lane holds W2[n=16t+m][k0..k0+7], k0 = ks*32+g*8.
    half8 bfr[5][3];
    #pragma unroll
    for (int t = 0; t < 5; ++t){
        #pragma unroll
        for (int ks = 0; ks < 3; ++ks){
            int k0 = ks*32 + g*8;
            half8 bv = {};
            if (k0 < 80) bv = *(const half8*)(w2p + (size_t)(16*t + m)*W2S + k0);
            bfr[t][ks] = bv;                     // k0>=80: A is zero there anyway
        }
    }
    __syncthreads();

    // stage chunk c (64 steps x 320B) into xpb[c&1] via global_load_lds.
    auto stage = [&](int c){
        float* buf = xpb[c & 1];
        const int base = c*64;
        #pragma unroll
        for (int k = 0; k < 20; ++k){
            int idx = k*64 + L;
            int cs  = idx / 20;
            int off = idx - cs*20;
            int tok = sX[base + cs];
            const float* src = embW + (size_t)tok*EW + off*4;
            __builtin_amdgcn_global_load_lds(
                (const __attribute__((address_space(1))) uint*)src,
                (__attribute__((address_space(3))) uint*)(buf + k*256),
                16, 0, 0);
        }
    };

    // bpermute byte-addresses (loop-invariant):
    // af0/af2 pair j <- src lane 2*(4g+j)  -> addr 32g+8j; af1: +128B
    int va0 = 32*g,      va1 = 32*g + 8,  va2 = 32*g + 16, va3 = 32*g + 24;
    int vb0 = va0 + 128, vb1 = va1 + 128, vb2 = va2 + 128, vb3 = va3 + 128;

    ushort* hout = h_all + (size_t)b*Sn*KP;
    const floatx4 zero4 = {};
    uint4 A0 = {}, A1 = {}, A2 = {};             // h_{-1} = 0

    stage(0);
    for (int c = 0; c < 8; ++c){
        __syncthreads();                 // chunk c landed (vmcnt drain, 1/64 steps)
        if (c < 7) stage(c + 1);         // async stage into the other buffer
        const float* xp = xpb[c & 1];
        // xp prefetch pipeline (2 deep), affine LDS addresses
        float x1c = xp[L];
        float x2c = (L < 16) ? xp[64 + L] : 0.f;
        float x1n = xp[80 + L];
        float x2n = (L < 16) ? xp[80 + 64 + L] : 0.f;
        #pragma unroll 2
        for (int t = 0; t < 64; ++t){
            int pf = (t + 2 < 64) ? t + 2 : 63;    // clamped slots never consumed
            float x1f = xp[pf*80 + L];
            float x2f = (L < 16) ? xp[pf*80 + 64 + L] : 0.f;

            half8 af0 = as_h8(A0), af1 = as_h8(A1), af2 = as_h8(A2);

            // y = W2 @ h : 5 tiles; ks0->ks1 chained, ks2 independent
            floatx4 c0, c1, c2, c3, c4, d0, d1, d2, d3, d4;
            c0 = __builtin_amdgcn_mfma_f32_16x16x32_f16(af0, bfr[0][0], zero4, 0,0,0);
            c1 = __builtin_amdgcn_mfma_f32_16x16x32_f16(af0, bfr[1][0], zero4, 0,0,0);
            c2 = __builtin_amdgcn_mfma_f32_16x16x32_f16(af0, bfr[2][0], zero4, 0,0,0);
            c3 = __builtin_amdgcn_mfma_f32_16x16x32_f16(af0, bfr[3][0], zero4, 0,0,0);
            c4 = __builtin_amdgcn_mfma_f32_16x16x32_f16(af0, bfr[4][0], zero4, 0,0,0);
            d0 = __builtin_amdgcn_mfma_f32_16x16x32_f16(af2, bfr[0][2], zero4, 0,0,0);
            d1 = __builtin_amdgcn_mfma_f32_16x16x32_f16(af2, bfr[1][2], zero4, 0,0,0);
            d2 = __builtin_amdgcn_mfma_f32_16x16x32_f16(af2, bfr[2][2], zero4, 0,0,0);
            d3 = __builtin_amdgcn_mfma_f32_16x16x32_f16(af2, bfr[3][2], zero4, 0,0,0);
            d4 = __builtin_amdgcn_mfma_f32_16x16x32_f16(af2, bfr[4][2], zero4, 0,0,0);
            c0 = __builtin_amdgcn_mfma_f32_16x16x32_f16(af1, bfr[0][1], c0, 0,0,0);
            c1 = __builtin_amdgcn_mfma_f32_16x16x32_f16(af1, bfr[1][1], c1, 0,0,0);
            c2 = __builtin_amdgcn_mfma_f32_16x16x32_f16(af1, bfr[2][1], c2, 0,0,0);
            c3 = __builtin_amdgcn_mfma_f32_16x16x32_f16(af1, bfr[3][1], c3, 0,0,0);
            c4 = __builtin_amdgcn_mfma_f32_16x16x32_f16(af1, bfr[4][1], c4, 0,0,0);

            // lane-local extraction (reg 0 = row 4g): y1 = cg[0]+dg[0]+x1c
            float yc = (L < 32) ? ((L < 16) ? c0[0] : c1[0])
                                : ((L < 48) ? c2[0] : c3[0]);
            float yd = (L < 32) ? ((L < 16) ? d0[0] : d1[0])
                                : ((L < 48) ? d2[0] : d3[0]);
            float h1 = sigmoid2f(yc + yd + x1c);
            ushort u1 = f2h(h1);
            int s = c*64 + t;
            hout[(size_t)s*KP + L] = u1;

            // pack q1 (even lanes valid) + issue A0/A1 bpermutes FIRST
            uint v1 = u1;
            uint pr1 = (uint)__builtin_amdgcn_update_dpp(0, (int)v1, 0xB1, 0xF, 0xF, true);
            int q1 = (int)(v1 | (pr1 << 16));
            A0.x = (uint)__builtin_amdgcn_ds_bpermute(va0, q1);
            A0.y = (uint)__builtin_amdgcn_ds_bpermute(va1, q1);
            A0.z = (uint)__builtin_amdgcn_ds_bpermute(va2, q1);
            A0.w = (uint)__builtin_amdgcn_ds_bpermute(va3, q1);
            A1.x = (uint)__builtin_amdgcn_ds_bpermute(vb0, q1);
            A1.y = (uint)__builtin_amdgcn_ds_bpermute(vb1, q1);
            A1.z = (uint)__builtin_amdgcn_ds_bpermute(vb2, q1);
            A1.w = (uint)__builtin_amdgcn_ds_bpermute(vb3, q1);

            // h2 (overlaps A0/A1 latency), then q2/A2
            float h2 = sigmoid2f(c4[0] + d4[0] + x2c);
            if (L >= 11) h2 = 0.f;               // cols 75..79 pad -> 0
            ushort u2 = f2h(h2);
            if (L < 16) hout[(size_t)s*KP + 64 + L] = u2;
            uint v2 = u2;
            uint pr2 = (uint)__builtin_amdgcn_update_dpp(0, (int)v2, 0xB1, 0xF, 0xF, true);
            int q2 = (int)(v2 | (pr2 << 16));
            A2.x = (uint)__builtin_amdgcn_ds_bpermute(va0, q2);
            A2.y = (uint)__builtin_amdgcn_ds_bpermute(va1, q2);
            A2.z = (uint)__builtin_amdgcn_ds_bpermute(va2, q2);
            A2.w = (uint)__builtin_amdgcn_ds_bpermute(va3, q2);

            x1c = x1n; x2c = x2n; x1n = x1f; x2n = x2f;
        }
    }
}

// ---------------------------------------------------------------------------
// Epilogue GEMM via MFMA 16x16x32 f16. Per block: 4 waves x 16 rows.
// Phase1: Z = H(16x96)@Wo^T + bo -> sigmoid -> O f16 in LDS (stride 104);
// Phase2: OUT = O@Wfc^T + bfc.
// C/D frag: col=lane&15, row=(lane>>4)*4+reg (m89-verified, dtype-indep).
// ---------------------------------------------------------------------------
__global__ __launch_bounds__(256) void k_out(
    const ushort* __restrict__ h_all, const ushort* __restrict__ woh,
    const ushort* __restrict__ wfh, const float* __restrict__ bo,
    const float* __restrict__ bfc, float* __restrict__ out)
{
    const int lane = threadIdx.x & 63;
    const int w    = threadIdx.x >> 6;
    const size_t r0 = (size_t)blockIdx.x*64 + w*16;
    const int m = lane & 15;
    const int g = lane >> 4;
    __shared__ __align__(16) ushort o_lds[4][16*104];
    ushort* ot = o_lds[w];
    // zero O pad cols 80..95 (read by k-step 2); wave-local, no barrier needed
    for (int i = lane; i < 128; i += 64){
        int row = i >> 3, cw = i & 7;
        *(uint*)&ot[row*104 + 80 + cw*2] = 0u;
    }
    // ---- Phase 1: Z = H @ Wo^T ----
    floatx4 acc1[5] = {};
    const ushort* hbase = h_all + r0*KP;
    #pragma unroll
    for (int ks = 0; ks < 3; ++ks){
        half8 a = *(const half8*)(hbase + (size_t)m*KP + ks*32 + g*8);
        #pragma unroll
        for (int t = 0; t < 5; ++t){
            half8 bt = *(const half8*)(woh + (16*t + m)*KP + ks*32 + g*8);
            acc1[t] = __builtin_amdgcn_mfma_f32_16x16x32_f16(a, bt, acc1[t], 0, 0, 0);
        }
    }
    // ---- bo + sigmoid -> O (f16, C layout) ----
    #pragma unroll
    for (int t = 0; t < 5; ++t){
        int n = 16*t + m;
        float bias = (n < Hn) ? bo[n] : 0.f;
        #pragma unroll
        for (int r = 0; r < 4; ++r){
            int row = g*4 + r;
            float o = 1.f/(1.f + __expf(-(acc1[t][r] + bias)));
            if (n >= Hn) o = 0.f;              // pad rows -> z=0 -> 0.5; kill
            ot[row*104 + n] = f2h(o);
        }
    }
    // wave-local LDS RAW: in-order DS pipe within a wave; no barrier
    // ---- Phase 2: OUT = O @ Wfc^T ----
    floatx4 acc2[8] = {};
    #pragma unroll
    for (int ks = 0; ks < 3; ++ks){
        half8 a = *(const half8*)(ot + m*104 + ks*32 + g*8);
        #pragma unroll
        for (int t = 0; t < 8; ++t){
            half8 bt = *(const half8*)(wfh + (16*t + m)*KP + ks*32 + g*8);
            acc2[t] = __builtin_amdgcn_mfma_f32_16x16x32_f16(a, bt, acc2[t], 0, 0, 0);
        }
    }
    // ---- bfc + store ----
    float* orow = out + r0*Ln;
    #pragma unroll
    for (int t = 0; t < 8; ++t){
        float bias = bfc[16*t + m];
        #pragma unroll
        for (int r = 0; r < 4; ++r){
            int row = g*4 + r;
            orow[(size_t)row*Ln + 16*t + m] = acc2[t][r] + bias;
        }
    }
}

extern "C" void kernel_launch(void* const* d_in, const int* in_sizes, int n_in,
                              void* d_out, int out_size, void* d_ws, size_t ws_size,
                              hipStream_t stream)
{
    const int*   X   = (const int*)d_in[0];
    const float* emb = (const float*)d_in[1];
    const float* W1  = (const float*)d_in[2];
    const float* b1  = (const float*)d_in[3];
    const float* W2  = (const float*)d_in[4];
    const float* b2  = (const float*)d_in[5];
    const float* Wo  = (const float*)d_in[6];
    const float* bo  = (const float*)d_in[7];
    const float* Wfc = (const float*)d_in[8];
    const float* bfc = (const float*)d_in[9];
    float* out = (float*)d_out;
    float* ws  = (float*)d_ws;

    float*  embW = ws + OFF_EMBW;
    ushort* hall = (ushort*)(ws + OFF_HALL);
    ushort* w2p  = (ushort*)(ws + OFF_W2P);
    ushort* woh  = (ushort*)(ws + OFF_WOH);
    ushort* wfh  = (ushort*)(ws + OFF_WFH);

    k_wprep<<<dim3(512), dim3(256), 0, stream>>>(W2, Wo, Wfc, w2p, woh, wfh, hall);
    k_embproj<<<dim3(Vn/64), dim3(256), 0, stream>>>(emb, W1, b1, b2, embW);
    k_rnn<<<dim3(Bn), dim3(64), 0, stream>>>(X, embW, w2p, hall);
    k_out<<<dim3((Bn*Sn)/64), dim3(256), 0, stream>>>(hall, woh, wfh, bo, bfc, out);
}

// Round 10
// 316.587 us; speedup vs baseline: 1.2502x; 1.0794x over previous
//
#include <hip/hip_runtime.h>
#include <hip/hip_bf16.h>

typedef unsigned int uint;
typedef unsigned short ushort;

constexpr int Bn = 256, Sn = 512, Vn = 32000, Dn = 100, Hn = 75, Ln = 128;
constexpr int EW = 80;    // embW row stride (floats), cols 75..79 zero
constexpr int KP = 96;    // h_all row stride (f16) = MFMA K-pad (3 x 32)
constexpr int W2S = 80;   // w2p row stride (f16)

// workspace layout (float units)
constexpr size_t OFF_EMBW = 0;                          // 32000*80   = 2,560,000 f
constexpr size_t OFF_HALL = OFF_EMBW + (size_t)Vn*EW;   // 131072*96 f16 = 6,291,456 f
constexpr size_t OFF_W2P  = OFF_HALL + (size_t)Bn*Sn*KP/2; // 80*80 f16 = 3200 f
constexpr size_t OFF_WOH  = OFF_W2P + 3200;             // 80*96 f16  = 3840 f
constexpr size_t OFF_WFH  = OFF_WOH + 3840;             // 128*96 f16 = 6144 f

typedef __attribute__((ext_vector_type(2))) _Float16 half2_t;
typedef __attribute__((ext_vector_type(8))) _Float16 half8;
typedef __attribute__((ext_vector_type(4))) float floatx4;

__device__ __forceinline__ ushort f2h(float f){
    union { _Float16 h; ushort u; } v; v.h = (_Float16)f; return v.u;
}
__device__ __forceinline__ half8 as_h8(uint4 u){
    union { uint4 u; half8 h; } v; v.u = u; return v.h;
}
__device__ __forceinline__ float sigmoidf(float z){
    return __builtin_amdgcn_rcpf(1.f + __expf(-z));
}

// ---------------------------------------------------------------------------
// Prep: W2 -> [80][80] f16 (pad 0), Wo -> [80][96] f16, Wfc -> [128][96] f16,
// zero h_all pad cols 80..95 (epilogue reads KP=96 cols).
// ---------------------------------------------------------------------------
__global__ __launch_bounds__(256) void k_wprep(
    const float* __restrict__ W2, const float* __restrict__ Wo,
    const float* __restrict__ Wfc, ushort* __restrict__ w2p,
    ushort* __restrict__ woh, ushort* __restrict__ wfh, ushort* __restrict__ h_all)
{
    const int tid = blockIdx.x*256 + threadIdx.x;
    const int stride = gridDim.x*256;
    for (int i = tid; i < 80*W2S; i += stride){
        int r = i / W2S, k = i % W2S;
        w2p[i] = (r < Hn && k < Hn) ? f2h(W2[r*Hn + k]) : (ushort)0;
    }
    for (int i = tid; i < 80*KP; i += stride){
        int r = i / KP, k = i % KP;
        woh[i] = (r < Hn && k < Hn) ? f2h(Wo[r*Hn + k]) : (ushort)0;
    }
    for (int i = tid; i < Ln*KP; i += stride){
        int l = i / KP, k = i % KP;
        wfh[i] = (k < Hn) ? f2h(Wfc[l*Hn + k]) : (ushort)0;
    }
    // h_all[row][80..95] = 0  (8 uints per row)
    uint* hu = (uint*)h_all;
    for (int i = tid; i < Bn*Sn*8; i += stride){
        int row = i >> 3, c = i & 7;
        hu[(size_t)row*48 + 40 + c] = 0u;
    }
}

// ---------------------------------------------------------------------------
// embW[v][j] = sum_d emb[v][d]*W1[j][d] + b1[j] + b2[j], stride EW=80.
// r7-proven: 4 waves/block, wave w owns col-group (j wave-uniform -> s_loads).
// ---------------------------------------------------------------------------
__global__ __attribute__((amdgpu_flat_work_group_size(256,256)))
__attribute__((amdgpu_waves_per_eu(1,1)))
void k_embproj(
    const float* __restrict__ emb, const float* __restrict__ W1,
    const float* __restrict__ b1, const float* __restrict__ b2,
    float* __restrict__ embW)
{
    const int lane = threadIdx.x & 63;
    const int w    = threadIdx.x >> 6;           // col-group 0..3
    const int v = blockIdx.x*64 + lane;
    const float4* ev = (const float4*)(emb + (size_t)v*Dn);
    float e[Dn];
    #pragma unroll
    for (int q = 0; q < Dn/4; ++q){
        float4 x = ev[q];
        e[4*q] = x.x; e[4*q+1] = x.y; e[4*q+2] = x.z; e[4*q+3] = x.w;
    }
    __shared__ float s_out[64*EW];
    const int j0 = w*19;
    const int jend = (w == 3) ? 18 : 19;         // w=3 covers 57..74
    #pragma unroll 2
    for (int jj = 0; jj < jend; ++jj){
        int j = j0 + jj;
        float a0 = b1[j] + b2[j], a1 = 0.f, a2 = 0.f, a3 = 0.f;
        const float* wp = W1 + j*Dn;             // wave-uniform -> s_loads
        #pragma unroll
        for (int d = 0; d < Dn; d += 4){
            a0 += wp[d]*e[d];     a1 += wp[d+1]*e[d+1];
            a2 += wp[d+2]*e[d+2]; a3 += wp[d+3]*e[d+3];
        }
        s_out[lane*EW + j] = (a0+a1) + (a2+a3);
    }
    if (w == 3){
        #pragma unroll
        for (int j = Hn; j < EW; ++j) s_out[lane*EW + j] = 0.f;
    }
    __syncthreads();
    float* dst = embW + (size_t)blockIdx.x*64*EW;
    for (int i = threadIdx.x; i < 64*EW; i += 256) dst[i] = s_out[i];
}

// ---------------------------------------------------------------------------
// FUSED scan + epilogue. 256 threads (4 waves), one block per batch row.
//  - Wave 0 runs the r6-EXACT MFMA recurrence (best measured: 164us; r8/r9
//    chain trims regressed and are reverted).
//  - ALL waves split the xp chunk staging 4-ways (5 global_load_lds each);
//    each wave drains its own vmcnt before the chunk barrier -> staged data
//    visible to wave 0 (m97 multi-wave pattern). Waves 1-3 then wait at the
//    next chunk barrier (same __syncthreads count as wave 0).
//  - After the scan: all 4 waves run the k_out body 8x over this row's 512
//    H-rows (same per-CU work as standalone k_out at 8 blocks/CU, but h_all
//    reads are same-CU L2-hot and one launch gap is removed).
//  - Diagnostic: total - this_kernel = wprep + embproj + launch gaps.
// ---------------------------------------------------------------------------
__global__ __attribute__((amdgpu_flat_work_group_size(256,256)))
__attribute__((amdgpu_waves_per_eu(1,1)))
void k_rnn(
    const int* __restrict__ X, const float* __restrict__ embW,
    const ushort* __restrict__ w2p, ushort* __restrict__ h_all,
    const ushort* __restrict__ woh, const ushort* __restrict__ wfh,
    const float* __restrict__ bo, const float* __restrict__ bfc,
    float* __restrict__ out)
{
    const int b   = blockIdx.x;
    const int tid = threadIdx.x;
    const int L   = tid & 63;
    const int wv  = tid >> 6;
    const int m   = L & 15;
    const int g   = L >> 4;
    __shared__ int sX[Sn];                         // 2 KB
    __shared__ __align__(16) float xpb[2][64*80];  // 40 KB xp double buffer
    __shared__ __align__(16) ushort o_lds[4][16*104]; // 13 KB epilogue O

    for (int i = tid; i < Sn; i += 256) sX[i] = X[b*Sn + i];

    // B-fragments (wave 0 only): lane holds W2[n=16t+m][k0..k0+7], k0=ks*32+g*8
    half8 bfr[5][3];
    if (wv == 0){
        #pragma unroll
        for (int t = 0; t < 5; ++t){
            #pragma unroll
            for (int ks = 0; ks < 3; ++ks){
                int k0 = ks*32 + g*8;
                half8 bv = {};
                if (k0 < 80) bv = *(const half8*)(w2p + (size_t)(16*t + m)*W2S + k0);
                bfr[t][ks] = bv;                 // k0>=80: A is zero there anyway
            }
        }
    }
    __syncthreads();

    // stage chunk c (64 steps x 320B) into xpb[c&1]; 4-way wave split:
    // idx = k*256+tid in [0,1280): row cs=idx/20, off=idx%20, dst byte idx*16
    // (per-wave base uniform; lane offset 16B matches global_load_lds HW).
    auto stage = [&](int c){
        float* buf = xpb[c & 1];
        const int base = c*64;
        #pragma unroll
        for (int k = 0; k < 5; ++k){
            int idx = k*256 + tid;
            int cs  = idx / 20;
            int off = idx - cs*20;
            int tok = sX[base + cs];
            const float* src = embW + (size_t)tok*EW + off*4;
            __builtin_amdgcn_global_load_lds(
                (const __attribute__((address_space(1))) uint*)src,
                (__attribute__((address_space(3))) uint*)(buf + idx*4),
                16, 0, 0);
        }
    };

    // bpermute byte-addresses (loop-invariant):
    // af0/af2 pair j <- src lane 2*(4g+j)  -> addr 32g+8j; af1: +128B
    int va0 = 32*g,      va1 = 32*g + 8,  va2 = 32*g + 16, va3 = 32*g + 24;
    int vb0 = va0 + 128, vb1 = va1 + 128, vb2 = va2 + 128, vb3 = va3 + 128;

    ushort* hout = h_all + (size_t)b*Sn*KP;
    const floatx4 zero4 = {};
    uint4 A0 = {}, A1 = {}, A2 = {};             // h_{-1} = 0

    stage(0);
    for (int c = 0; c < 8; ++c){
        __syncthreads();                 // chunk c landed (each wave drained own vmcnt)
        if (c < 7) stage(c + 1);         // async stage into the other buffer (all waves)
        if (wv == 0){
            const float* xp = xpb[c & 1];
            // xp prefetch pipeline (2 deep), affine LDS addresses
            float x1c = xp[L];
            float x2c = (L < 16) ? xp[64 + L] : 0.f;
            float x1n = xp[80 + L];
            float x2n = (L < 16) ? xp[80 + 64 + L] : 0.f;
            for (int t = 0; t < 64; ++t){
                int pf = (t + 2 < 64) ? t + 2 : 63;  // clamped slots never consumed
                float x1f = xp[pf*80 + L];
                float x2f = (L < 16) ? xp[pf*80 + 64 + L] : 0.f;

                half8 af0 = as_h8(A0), af1 = as_h8(A1), af2 = as_h8(A2);

                // y = W2 @ h : 5 output tiles x 3 K-steps (r6-exact chaining)
                floatx4 acc0, acc1, acc2, acc3, acc4;
                acc0 = __builtin_amdgcn_mfma_f32_16x16x32_f16(af0, bfr[0][0], zero4, 0,0,0);
                acc1 = __builtin_amdgcn_mfma_f32_16x16x32_f16(af0, bfr[1][0], zero4, 0,0,0);
                acc2 = __builtin_amdgcn_mfma_f32_16x16x32_f16(af0, bfr[2][0], zero4, 0,0,0);
                acc3 = __builtin_amdgcn_mfma_f32_16x16x32_f16(af0, bfr[3][0], zero4, 0,0,0);
                acc4 = __builtin_amdgcn_mfma_f32_16x16x32_f16(af0, bfr[4][0], zero4, 0,0,0);
                acc0 = __builtin_amdgcn_mfma_f32_16x16x32_f16(af1, bfr[0][1], acc0, 0,0,0);
                acc1 = __builtin_amdgcn_mfma_f32_16x16x32_f16(af1, bfr[1][1], acc1, 0,0,0);
                acc2 = __builtin_amdgcn_mfma_f32_16x16x32_f16(af1, bfr[2][1], acc2, 0,0,0);
                acc3 = __builtin_amdgcn_mfma_f32_16x16x32_f16(af1, bfr[3][1], acc3, 0,0,0);
                acc4 = __builtin_amdgcn_mfma_f32_16x16x32_f16(af1, bfr[4][1], acc4, 0,0,0);
                acc0 = __builtin_amdgcn_mfma_f32_16x16x32_f16(af2, bfr[0][2], acc0, 0,0,0);
                acc1 = __builtin_amdgcn_mfma_f32_16x16x32_f16(af2, bfr[1][2], acc1, 0,0,0);
                acc2 = __builtin_amdgcn_mfma_f32_16x16x32_f16(af2, bfr[2][2], acc2, 0,0,0);
                acc3 = __builtin_amdgcn_mfma_f32_16x16x32_f16(af2, bfr[3][2], acc3, 0,0,0);
                acc4 = __builtin_amdgcn_mfma_f32_16x16x32_f16(af2, bfr[4][2], acc4, 0,0,0);

                // lane-local extraction: y[L] = acc_g[0]; y[64+m] = acc4[0]
                float y1 = (L < 32) ? ((L < 16) ? acc0[0] : acc1[0])
                                    : ((L < 48) ? acc2[0] : acc3[0]);
                float y2 = acc4[0];

                float h1 = sigmoidf(y1 + x1c);
                float h2 = sigmoidf(y2 + x2c);
                if (L >= 11) h2 = 0.f;               // cols 75..79 pad -> 0
                ushort u1 = f2h(h1);
                ushort u2 = f2h(h2);
                int s = c*64 + t;
                hout[(size_t)s*KP + L] = u1;
                if (L < 16) hout[(size_t)s*KP + 64 + L] = u2;

                // pair adjacent lanes' f16 via DPP quad_perm [1,0,3,2]
                uint v1 = u1, v2 = u2;
                uint pr1 = (uint)__builtin_amdgcn_update_dpp(0, (int)v1, 0xB1, 0xF, 0xF, true);
                uint pr2 = (uint)__builtin_amdgcn_update_dpp(0, (int)v2, 0xB1, 0xF, 0xF, true);
                int q1 = (int)(v1 | (pr1 << 16));
                int q2 = (int)(v2 | (pr2 << 16));

                // rebuild A-fragments for step s+1: 12 independent bpermutes
                A0.x = (uint)__builtin_amdgcn_ds_bpermute(va0, q1);
                A0.y = (uint)__builtin_amdgcn_ds_bpermute(va1, q1);
                A0.z = (uint)__builtin_amdgcn_ds_bpermute(va2, q1);
                A0.w = (uint)__builtin_amdgcn_ds_bpermute(va3, q1);
                A1.x = (uint)__builtin_amdgcn_ds_bpermute(vb0, q1);
                A1.y = (uint)__builtin_amdgcn_ds_bpermute(vb1, q1);
                A1.z = (uint)__builtin_amdgcn_ds_bpermute(vb2, q1);
                A1.w = (uint)__builtin_amdgcn_ds_bpermute(vb3, q1);
                A2.x = (uint)__builtin_amdgcn_ds_bpermute(va0, q2);
                A2.y = (uint)__builtin_amdgcn_ds_bpermute(va1, q2);
                A2.z = (uint)__builtin_amdgcn_ds_bpermute(va2, q2);
                A2.w = (uint)__builtin_amdgcn_ds_bpermute(va3, q2);

                x1c = x1n; x2c = x2n; x1n = x1f; x2n = x2f;
            }
        }
    }
    __syncthreads();                     // h_all[b] complete & visible

    // ---- fused epilogue: k_out body, 8 x 64-row chunks of this batch row ----
    ushort* ot = o_lds[wv];
    // zero O pad cols 80..95 once (cols 0..79 rewritten each iteration)
    for (int i = L; i < 128; i += 64){
        int row = i >> 3, cw = i & 7;
        *(uint*)&ot[row*104 + 80 + cw*2] = 0u;
    }
    for (int it = 0; it < 8; ++it){
        const size_t r0 = (size_t)b*Sn + it*64 + wv*16;
        // Phase 1: Z = H @ Wo^T
        floatx4 acc1[5] = {};
        const ushort* hbase = h_all + r0*KP;
        #pragma unroll
        for (int ks = 0; ks < 3; ++ks){
            half8 a = *(const half8*)(hbase + (size_t)m*KP + ks*32 + g*8);
            #pragma unroll
            for (int t = 0; t < 5; ++t){
                half8 bt = *(const half8*)(woh + (16*t + m)*KP + ks*32 + g*8);
                acc1[t] = __builtin_amdgcn_mfma_f32_16x16x32_f16(a, bt, acc1[t], 0, 0, 0);
            }
        }
        // bo + sigmoid -> O (f16, C layout)
        #pragma unroll
        for (int t = 0; t < 5; ++t){
            int n = 16*t + m;
            float bias = (n < Hn) ? bo[n] : 0.f;
            #pragma unroll
            for (int r = 0; r < 4; ++r){
                int row = g*4 + r;
                float o = sigmoidf(acc1[t][r] + bias);
                if (n >= Hn) o = 0.f;            // pad rows -> z=0 -> 0.5; kill
                ot[row*104 + n] = f2h(o);
            }
        }
        // wave-local LDS RAW: in-order DS pipe within a wave; no barrier
        // Phase 2: OUT = O @ Wfc^T
        floatx4 acc2[8] = {};
        #pragma unroll
        for (int ks = 0; ks < 3; ++ks){
            half8 a = *(const half8*)(ot + m*104 + ks*32 + g*8);
            #pragma unroll
            for (int t = 0; t < 8; ++t){
                half8 bt = *(const half8*)(wfh + (16*t + m)*KP + ks*32 + g*8);
                acc2[t] = __builtin_amdgcn_mfma_f32_16x16x32_f16(a, bt, acc2[t], 0, 0, 0);
            }
        }
        // bfc + store
        float* orow = out + r0*Ln;
        #pragma unroll
        for (int t = 0; t < 8; ++t){
            float bias = bfc[16*t + m];
            #pragma unroll
            for (int r = 0; r < 4; ++r){
                int row = g*4 + r;
                orow[(size_t)row*Ln + 16*t + m] = acc2[t][r] + bias;
            }
        }
    }
}

extern "C" void kernel_launch(void* const* d_in, const int* in_sizes, int n_in,
                              void* d_out, int out_size, void* d_ws, size_t ws_size,
                              hipStream_t stream)
{
    const int*   X   = (const int*)d_in[0];
    const float* emb = (const float*)d_in[1];
    const float* W1  = (const float*)d_in[2];
    const float* b1  = (const float*)d_in[3];
    const float* W2  = (const float*)d_in[4];
    const float* b2  = (const float*)d_in[5];
    const float* Wo  = (const float*)d_in[6];
    const float* bo  = (const float*)d_in[7];
    const float* Wfc = (const float*)d_in[8];
    const float* bfc = (const float*)d_in[9];
    float* out = (float*)d_out;
    float* ws  = (float*)d_ws;

    float*  embW = ws + OFF_EMBW;
    ushort* hall = (ushort*)(ws + OFF_HALL);
    ushort* w2p  = (ushort*)(ws + OFF_W2P);
    ushort* woh  = (ushort*)(ws + OFF_WOH);
    ushort* wfh  = (ushort*)(ws + OFF_WFH);

    k_wprep<<<dim3(512), dim3(256), 0, stream>>>(W2, Wo, Wfc, w2p, woh, wfh, hall);
    k_embproj<<<dim3(Vn/64), dim3(256), 0, stream>>>(emb, W1, b1, b2, embW);
    k_rnn<<<dim3(Bn), dim3(256), 0, stream>>>(X, embW, w2p, hall, woh, wfh, bo, bfc, out);
}